// Round 15
// baseline (227.115 us; speedup 1.0000x reference)
//
#include <hip/hip_runtime.h>
#include <hip/hip_bf16.h>
#include <cstdint>

#define CIN   128
#define COUT  256
#define BATCH 16
#define HH    64
#define WW    64
#define TH    32
#define TW    32
#define NT    (BATCH*TH*TW)   /* 16384 winograd tiles */
#define APQ   (COUT*CIN)      /* U plane: 32768 elems */
#define BPQ   (NT*CIN)        /* V plane: 2097152 elems */

typedef __bf16 bf16x8 __attribute__((ext_vector_type(8)));
typedef float  f32x4  __attribute__((ext_vector_type(4)));
typedef float  f32x16 __attribute__((ext_vector_type(16)));

__device__ __forceinline__ void gload16(const void* g, void* l) {
    __builtin_amdgcn_global_load_lds(
        (const __attribute__((address_space(1))) uint32_t*)g,
        (__attribute__((address_space(3))) uint32_t*)l, 16, 0, 0);
}

// ---------------------------------------------------------------------------
// Kernel 1: weight transform  U[pq][k][c] = (G w G^T)[p][q], bf16
// ---------------------------------------------------------------------------
__global__ __launch_bounds__(256) void wg_wtrans(const float* __restrict__ w,
                                                 __hip_bfloat16* __restrict__ U) {
    int idx = blockIdx.x * 256 + threadIdx.x;       // idx = k*CIN + c
    if (idx >= COUT * CIN) return;
    const float* wp = w + idx * 9;
    float g[3][3];
#pragma unroll
    for (int x = 0; x < 3; x++)
#pragma unroll
        for (int y = 0; y < 3; y++) g[x][y] = wp[x * 3 + y];

    float t[4][3];
#pragma unroll
    for (int y = 0; y < 3; y++) {
        t[0][y] = g[0][y];
        t[1][y] = 0.5f * (g[0][y] + g[1][y] + g[2][y]);
        t[2][y] = 0.5f * (g[0][y] - g[1][y] + g[2][y]);
        t[3][y] = g[2][y];
    }
#pragma unroll
    for (int p = 0; p < 4; p++) {
        float u0 = t[p][0];
        float u1 = 0.5f * (t[p][0] + t[p][1] + t[p][2]);
        float u2 = 0.5f * (t[p][0] - t[p][1] + t[p][2]);
        float u3 = t[p][2];
        U[(p * 4 + 0) * APQ + idx] = __float2bfloat16(u0);
        U[(p * 4 + 1) * APQ + idx] = __float2bfloat16(u1);
        U[(p * 4 + 2) * APQ + idx] = __float2bfloat16(u2);
        U[(p * 4 + 3) * APQ + idx] = __float2bfloat16(u3);
    }
}

// ---------------------------------------------------------------------------
// Kernel 2: input transform, full-row blocks.
// Block (i, b), 1024 thr = (c 128, jj 8), each thread does 4 j's.
// Fixes partial-cacheline V writes: one block writes complete 256B V rows
// (wave = 64 consecutive c -> 128B contiguous; both waves of a row in-block).
// X staged in LDS as bf16, stride 266 (bank-friendly), float4 global loads.
// ---------------------------------------------------------------------------
__global__ __launch_bounds__(1024) void wg_itrans2(const float* __restrict__ X,
                                                   __hip_bfloat16* __restrict__ V) {
    __shared__ __hip_bfloat16 Xp[128 * 266];    // ~68 KB
    const int i = blockIdx.x;
    const int b = blockIdx.y;
    const int tid = threadIdx.x;

    // zero the x=-1 / x=64 border columns (128c * 4r * 2 = 1024 = blockDim)
    {
        int c = tid >> 3, r = (tid >> 1) & 3, e = tid & 1;
        Xp[c * 266 + r * 66 + e * 65] = __float2bfloat16(0.f);
    }
    // main load: rows y = 2i-1+r, float4-coalesced in x
#pragma unroll
    for (int it = 0; it < 8; ++it) {
        int flat = it * 4096 + tid * 4;
        int c = flat >> 8, r = (flat >> 6) & 3, x = flat & 63;
        int y = 2 * i - 1 + r;
        float4 v = make_float4(0.f, 0.f, 0.f, 0.f);
        if (y >= 0 && y < HH)
            v = *reinterpret_cast<const float4*>(&X[(((b * CIN + c) * HH + y) << 6) + x]);
        int base = c * 266 + r * 66 + 1 + x;
        Xp[base + 0] = __float2bfloat16(v.x);
        Xp[base + 1] = __float2bfloat16(v.y);
        Xp[base + 2] = __float2bfloat16(v.z);
        Xp[base + 3] = __float2bfloat16(v.w);
    }
    __syncthreads();

    const int c  = tid & 127;
    const int jj = tid >> 7;
#pragma unroll
    for (int jl = 0; jl < 4; ++jl) {
        const int j = jj * 4 + jl;
        float d[4][4];
#pragma unroll
        for (int r = 0; r < 4; r++) {
            int off = c * 266 + r * 66 + 2 * j;   // even -> 4B-aligned pairs
            ushort2 s01 = *reinterpret_cast<const ushort2*>(&Xp[off]);
            ushort2 s23 = *reinterpret_cast<const ushort2*>(&Xp[off + 2]);
            d[r][0] = __bfloat162float(*reinterpret_cast<__hip_bfloat16*>(&s01.x));
            d[r][1] = __bfloat162float(*reinterpret_cast<__hip_bfloat16*>(&s01.y));
            d[r][2] = __bfloat162float(*reinterpret_cast<__hip_bfloat16*>(&s23.x));
            d[r][3] = __bfloat162float(*reinterpret_cast<__hip_bfloat16*>(&s23.y));
        }
        float t0[4], t1[4], t2[4], t3[4];
#pragma unroll
        for (int y = 0; y < 4; y++) {
            t0[y] = d[0][y] - d[2][y];
            t1[y] = d[1][y] + d[2][y];
            t2[y] = d[2][y] - d[1][y];
            t3[y] = d[1][y] - d[3][y];
        }
        float vm[4][4];
#pragma unroll
        for (int p = 0; p < 4; p++) {
            const float* tp = (p == 0) ? t0 : (p == 1) ? t1 : (p == 2) ? t2 : t3;
            vm[p][0] = tp[0] - tp[2];
            vm[p][1] = tp[1] + tp[2];
            vm[p][2] = tp[2] - tp[1];
            vm[p][3] = tp[1] - tp[3];
        }
        const int bij = (b << 10) + (i << 5) + j;
        const size_t vo = (size_t)bij * CIN + c;
#pragma unroll
        for (int p = 0; p < 4; p++)
#pragma unroll
            for (int q = 0; q < 4; q++)
                V[(size_t)(p * 4 + q) * BPQ + vo] = __float2bfloat16(vm[p][q]);
    }
}

// ---------------------------------------------------------------------------
// Kernel 3: fused GEMM + output transform — 16 waves/CU via 32x32 MFMA.
// Block [128 kout x 64 bij], 512 thr = 8 waves (4m x 2n), wave tile 32x32
// = ONE v_mfma_f32_32x32x16_bf16 frag (yac 4x16=64 + mac 16 regs -> fits
// 128 VGPR -> 4 waves/SIMD). LDS 3 bufs x 24KB = 72KB -> 2 blocks/CU
// co-resident = 16 waves/CU (the TLP every 8-wave config lacked).
// 32 slots (pq=t>>1, kb=(t&1)*64). Stage = 3 gload16/thread, depth 2;
// ledger: stage(t+2) issued FIRST, then vmcnt(3) drains t+1 (so buf t AND
// t+1 resident). 8 interleaved ds_reads; pipelined lgkmcnt(6/4/2/0), each
// followed by sched_barrier(0) (rule 18). XOR granule swizzle (R13-verified
// conflict-free). Fold into 4 Y planes every 2nd slot, compile-time weights.
// ---------------------------------------------------------------------------
#define ABY  16384
#define BUFB 24576

__global__ __launch_bounds__(512, 4) void wg_gemm15(const __hip_bfloat16* __restrict__ U,
                                                    const __hip_bfloat16* __restrict__ V,
                                                    const float* __restrict__ bias,
                                                    float* __restrict__ out) {
    __shared__ char lds[3 * BUFB];       // 72 KB

    // bijective XCD swizzle (512 % 8 == 0); mt-pairs (shared V) on same XCD
    int orig = blockIdx.x;
    int wgid = (orig & 7) * 64 + (orig >> 3);
    const int mt = wgid & 1, nt = wgid >> 1;
    const int m0 = mt * 128, n0 = nt * 64;

    const int tid  = threadIdx.x;
    const int lane = tid & 63;
    const int wave = tid >> 6;
    const int wm = wave >> 1, wn = wave & 1;
    const int l31 = lane & 31, l7 = lane & 7, kg = lane >> 5;

    // staging: chunk c -> row R=c>>3, slot s=c&7 holds granule g=s^(R&7)
    const __hip_bfloat16 *paA0, *paA1, *pbB;
    int ldsA0, ldsA1, ldsB0;
    {
        int c0 = tid,        R0 = c0 >> 3, G0 = (c0 & 7) ^ (R0 & 7);
        int c1 = tid + 512,  R1 = c1 >> 3, G1 = (c1 & 7) ^ (R1 & 7);
        paA0 = U + (m0 + R0) * CIN + G0 * 8;  ldsA0 = c0 * 16;
        paA1 = U + (m0 + R1) * CIN + G1 * 8;  ldsA1 = c1 * 16;
        // B: rows R0 (0..63)
        pbB  = V + (size_t)(n0 + R0) * CIN + G0 * 8;  ldsB0 = ABY + c0 * 16;
    }

    // ds_read offsets: row r, granule g=kk*2+kg -> byte r*128 + ((g^(r&7))<<4)
    int aoff[4], boff[4];
#pragma unroll
    for (int kk = 0; kk < 4; kk++) {
        int g = (kk * 2 + kg) ^ l7;
        aoff[kk] = (wm * 32 + l31) * 128 + (g << 4);
        boff[kk] = ABY + (wn * 32 + l31) * 128 + (g << 4);
    }

    f32x16 y00 = (f32x16)(0.f), y01 = (f32x16)(0.f);
    f32x16 y10 = (f32x16)(0.f), y11 = (f32x16)(0.f);
    f32x16 mac;
    const f32x16 fz = (f32x16)(0.f);

    auto stage = [&](int s) {
        char* sb = lds + (s % 3) * BUFB;
        const int pq = s >> 1, kb = (s & 1) * 64;
        gload16(paA0 + pq * APQ + kb, sb + ldsA0);
        gload16(paA1 + pq * APQ + kb, sb + ldsA1);
        gload16(pbB + (size_t)pq * BPQ + kb, sb + ldsB0);
    };

    auto fold = [&](int pq) {            // compile-time pq under full unroll
        const int p = pq >> 2, q = pq & 3;
        const float s1p = (p >= 2) ? -1.f : 1.f;
        const float s1q = (q >= 2) ? -1.f : 1.f;
        if (p != 3 && q != 3) y00 += mac;
        if (p != 3 && q != 0) y01 += s1q * mac;
        if (p != 0 && q != 3) y10 += s1p * mac;
        if (p != 0 && q != 0) y11 += (s1p * s1q) * mac;
    };

    // prologue: 2 stages in flight
    stage(0);
    stage(1);

#pragma unroll
    for (int t = 0; t < 32; ++t) {
        if (t <= 29) stage(t + 2);       // issue FIRST (ledger)
        if (t >= 2 && (t & 1) == 0) fold((t >> 1) - 1);

        if (t <= 30) asm volatile("s_waitcnt vmcnt(3)");   // buf t (and t+1) resident
        else         asm volatile("s_waitcnt vmcnt(0)");
        __builtin_amdgcn_s_barrier();
        __builtin_amdgcn_sched_barrier(0);

        const char* rb = lds + (t % 3) * BUFB;
        bf16x8 a0 = *reinterpret_cast<const bf16x8*>(rb + aoff[0]);
        bf16x8 b0 = *reinterpret_cast<const bf16x8*>(rb + boff[0]);
        bf16x8 a1 = *reinterpret_cast<const bf16x8*>(rb + aoff[1]);
        bf16x8 b1 = *reinterpret_cast<const bf16x8*>(rb + boff[1]);
        bf16x8 a2 = *reinterpret_cast<const bf16x8*>(rb + aoff[2]);
        bf16x8 b2 = *reinterpret_cast<const bf16x8*>(rb + boff[2]);
        bf16x8 a3 = *reinterpret_cast<const bf16x8*>(rb + aoff[3]);
        bf16x8 b3 = *reinterpret_cast<const bf16x8*>(rb + boff[3]);
        __builtin_amdgcn_sched_barrier(0);

        const bool init = (t & 1) == 0;
        asm volatile("s_waitcnt lgkmcnt(6)");
        __builtin_amdgcn_sched_barrier(0);
        __builtin_amdgcn_s_setprio(1);
        mac = __builtin_amdgcn_mfma_f32_32x32x16_bf16(a0, b0, init ? fz : mac, 0, 0, 0);
        __builtin_amdgcn_s_setprio(0);
        asm volatile("s_waitcnt lgkmcnt(4)");
        __builtin_amdgcn_sched_barrier(0);
        __builtin_amdgcn_s_setprio(1);
        mac = __builtin_amdgcn_mfma_f32_32x32x16_bf16(a1, b1, mac, 0, 0, 0);
        __builtin_amdgcn_s_setprio(0);
        asm volatile("s_waitcnt lgkmcnt(2)");
        __builtin_amdgcn_sched_barrier(0);
        __builtin_amdgcn_s_setprio(1);
        mac = __builtin_amdgcn_mfma_f32_32x32x16_bf16(a2, b2, mac, 0, 0, 0);
        __builtin_amdgcn_s_setprio(0);
        asm volatile("s_waitcnt lgkmcnt(0)");
        __builtin_amdgcn_sched_barrier(0);
        __builtin_amdgcn_s_setprio(1);
        mac = __builtin_amdgcn_mfma_f32_32x32x16_bf16(a3, b3, mac, 0, 0, 0);
        __builtin_amdgcn_s_setprio(0);
        __builtin_amdgcn_sched_barrier(0);
        __builtin_amdgcn_s_barrier();
    }
    fold(15);

    // ---- writeout: 32x32 D frag: col=lane&31, row=(r&3)+8*(r>>2)+4*(lane>>5)
    const int bij = n0 + wn * 32 + l31;
    const int bb = bij >> 10, ti = (bij >> 5) & 31, tj = bij & 31;
#pragma unroll
    for (int r = 0; r < 16; r++) {
        const int row  = (r & 3) + 8 * (r >> 2) + 4 * kg;
        const int kout = m0 + wm * 32 + row;
        const float bvv = bias[kout];
        float* op = out + (((size_t)bb * COUT + kout) * HH + 2 * ti) * WW + 2 * tj;
        *reinterpret_cast<float2*>(op)      = make_float2(y00[r] + bvv, y01[r] + bvv);
        *reinterpret_cast<float2*>(op + WW) = make_float2(y10[r] + bvv, y11[r] + bvv);
    }
}

// ---------------------------------------------------------------------------
extern "C" void kernel_launch(void* const* d_in, const int* in_sizes, int n_in,
                              void* d_out, int out_size, void* d_ws, size_t ws_size,
                              hipStream_t stream) {
    const float* X    = (const float*)d_in[0];
    const float* w    = (const float*)d_in[1];
    const float* bias = (const float*)d_in[2];
    float* out        = (float*)d_out;

    __hip_bfloat16* U = (__hip_bfloat16*)d_ws;                       // 1 MB
    __hip_bfloat16* V = (__hip_bfloat16*)((char*)d_ws + (1u << 20)); // 64 MB

    wg_wtrans<<<(COUT * CIN + 255) / 256, 256, 0, stream>>>(w, U);
    wg_itrans2<<<dim3(TH, BATCH), 1024, 0, stream>>>(X, V);
    wg_gemm15<<<(COUT / 128) * (NT / 64), 512, 0, stream>>>(U, V, bias, out);
}

// Round 16
// 67.436 us; speedup vs baseline: 3.3679x; 3.3679x over previous
//
#include <hip/hip_runtime.h>
#include <hip/hip_bf16.h>
#include <cstdint>

#define CIN   128
#define COUT  256
#define BATCH 16
#define HH    64
#define WW    64
#define TH    32
#define TW    32
#define NT    (BATCH*TH*TW)   /* 16384 winograd tiles */
#define APQ   (COUT*CIN)      /* U plane: 32768 elems */
#define BPQ   (NT*CIN)        /* V plane: 2097152 elems */

typedef __bf16 bf16x8 __attribute__((ext_vector_type(8)));
typedef float  f32x4  __attribute__((ext_vector_type(4)));

__device__ __forceinline__ void gload16(const void* g, void* l) {
    __builtin_amdgcn_global_load_lds(
        (const __attribute__((address_space(1))) uint32_t*)g,
        (__attribute__((address_space(3))) uint32_t*)l, 16, 0, 0);
}

// ---------------------------------------------------------------------------
// Kernel 1: weight transform  U[pq][k][c] = (G w G^T)[p][q], bf16
// ---------------------------------------------------------------------------
__global__ __launch_bounds__(256) void wg_wtrans(const float* __restrict__ w,
                                                 __hip_bfloat16* __restrict__ U) {
    int idx = blockIdx.x * 256 + threadIdx.x;       // idx = k*CIN + c
    if (idx >= COUT * CIN) return;
    const float* wp = w + idx * 9;
    float g[3][3];
#pragma unroll
    for (int x = 0; x < 3; x++)
#pragma unroll
        for (int y = 0; y < 3; y++) g[x][y] = wp[x * 3 + y];

    float t[4][3];
#pragma unroll
    for (int y = 0; y < 3; y++) {
        t[0][y] = g[0][y];
        t[1][y] = 0.5f * (g[0][y] + g[1][y] + g[2][y]);
        t[2][y] = 0.5f * (g[0][y] - g[1][y] + g[2][y]);
        t[3][y] = g[2][y];
    }
#pragma unroll
    for (int p = 0; p < 4; p++) {
        float u0 = t[p][0];
        float u1 = 0.5f * (t[p][0] + t[p][1] + t[p][2]);
        float u2 = 0.5f * (t[p][0] - t[p][1] + t[p][2]);
        float u3 = t[p][2];
        U[(p * 4 + 0) * APQ + idx] = __float2bfloat16(u0);
        U[(p * 4 + 1) * APQ + idx] = __float2bfloat16(u1);
        U[(p * 4 + 2) * APQ + idx] = __float2bfloat16(u2);
        U[(p * 4 + 3) * APQ + idx] = __float2bfloat16(u3);
    }
}

// ---------------------------------------------------------------------------
// Kernel 2: input transform, full-row blocks (R15 itrans2, correctness-
// verified). Block (i, b), 1024 thr = (c 128, jj 8), each thread does 4 j's.
// Every wave-store of V is 128 B contiguous (64 consecutive c per wave).
// X staged in LDS as bf16, stride 266, float4 global loads.
// ---------------------------------------------------------------------------
__global__ __launch_bounds__(1024) void wg_itrans2(const float* __restrict__ X,
                                                   __hip_bfloat16* __restrict__ V) {
    __shared__ __hip_bfloat16 Xp[128 * 266];    // ~68 KB
    const int i = blockIdx.x;
    const int b = blockIdx.y;
    const int tid = threadIdx.x;

    // zero the x=-1 / x=64 border columns (128c * 4r * 2 = 1024 = blockDim)
    {
        int c = tid >> 3, r = (tid >> 1) & 3, e = tid & 1;
        Xp[c * 266 + r * 66 + e * 65] = __float2bfloat16(0.f);
    }
    // main load: rows y = 2i-1+r, float4-coalesced in x
#pragma unroll
    for (int it = 0; it < 8; ++it) {
        int flat = it * 4096 + tid * 4;
        int c = flat >> 8, r = (flat >> 6) & 3, x = flat & 63;
        int y = 2 * i - 1 + r;
        float4 v = make_float4(0.f, 0.f, 0.f, 0.f);
        if (y >= 0 && y < HH)
            v = *reinterpret_cast<const float4*>(&X[(((b * CIN + c) * HH + y) << 6) + x]);
        int base = c * 266 + r * 66 + 1 + x;
        Xp[base + 0] = __float2bfloat16(v.x);
        Xp[base + 1] = __float2bfloat16(v.y);
        Xp[base + 2] = __float2bfloat16(v.z);
        Xp[base + 3] = __float2bfloat16(v.w);
    }
    __syncthreads();

    const int c  = tid & 127;
    const int jj = tid >> 7;
#pragma unroll
    for (int jl = 0; jl < 4; ++jl) {
        const int j = jj * 4 + jl;
        float d[4][4];
#pragma unroll
        for (int r = 0; r < 4; r++) {
            int off = c * 266 + r * 66 + 2 * j;   // even -> 4B-aligned pairs
            ushort2 s01 = *reinterpret_cast<const ushort2*>(&Xp[off]);
            ushort2 s23 = *reinterpret_cast<const ushort2*>(&Xp[off + 2]);
            d[r][0] = __bfloat162float(*reinterpret_cast<__hip_bfloat16*>(&s01.x));
            d[r][1] = __bfloat162float(*reinterpret_cast<__hip_bfloat16*>(&s01.y));
            d[r][2] = __bfloat162float(*reinterpret_cast<__hip_bfloat16*>(&s23.x));
            d[r][3] = __bfloat162float(*reinterpret_cast<__hip_bfloat16*>(&s23.y));
        }
        float t0[4], t1[4], t2[4], t3[4];
#pragma unroll
        for (int y = 0; y < 4; y++) {
            t0[y] = d[0][y] - d[2][y];
            t1[y] = d[1][y] + d[2][y];
            t2[y] = d[2][y] - d[1][y];
            t3[y] = d[1][y] - d[3][y];
        }
        float vm[4][4];
#pragma unroll
        for (int p = 0; p < 4; p++) {
            const float* tp = (p == 0) ? t0 : (p == 1) ? t1 : (p == 2) ? t2 : t3;
            vm[p][0] = tp[0] - tp[2];
            vm[p][1] = tp[1] + tp[2];
            vm[p][2] = tp[2] - tp[1];
            vm[p][3] = tp[1] - tp[3];
        }
        const int bij = (b << 10) + (i << 5) + j;
        const size_t vo = (size_t)bij * CIN + c;
#pragma unroll
        for (int p = 0; p < 4; p++)
#pragma unroll
            for (int q = 0; q < 4; q++)
                V[(size_t)(p * 4 + q) * BPQ + vo] = __float2bfloat16(vm[p][q]);
    }
}

// ---------------------------------------------------------------------------
// Kernel 3: fused GEMM + output transform — R13 verified (unchanged).
// Block [128 kout x 128 bij], 512 thr = 8 waves (2m x 4n), wave tile 64x32.
// Grid 256 = 1/CU, non-overlapping. 32 slots, counted vmcnt(8)/lgkm(6),
// 4 LDS buffers depth-3, XOR granule swizzle, named kk0 double-buffer.
// ---------------------------------------------------------------------------
#define ABYTES 16384
#define BUFSZ  32768

__global__ __launch_bounds__(512, 2) void wg_gemm13(const __hip_bfloat16* __restrict__ U,
                                                    const __hip_bfloat16* __restrict__ V,
                                                    const float* __restrict__ bias,
                                                    float* __restrict__ out) {
    __shared__ char lds[4 * BUFSZ];      // 128 KB

    // bijective XCD swizzle (256 % 8 == 0): 32 consecutive wg per XCD
    int orig = blockIdx.x;
    int wgid = (orig & 7) * 32 + (orig >> 3);
    const int mt = wgid & 1, nt = wgid >> 1;
    const int m0 = mt * 128, n0 = nt * 128;

    const int tid  = threadIdx.x;
    const int lane = tid & 63;
    const int wave = tid >> 6;
    const int wm = wave >> 2, wn = wave & 3;

    // staging: chunk c holds tile granule (row R=c>>3, gran G=(c&7)^(R&7))
    const __hip_bfloat16* pa[2];
    const __hip_bfloat16* pb[2];
    int ldsA[2], ldsB[2];
#pragma unroll
    for (int ch = 0; ch < 2; ch++) {
        int c = ch * 512 + tid;
        int R = c >> 3;
        int G = (c & 7) ^ (R & 7);
        pa[ch] = U + (m0 + R) * CIN + G * 8;
        pb[ch] = V + (size_t)(n0 + R) * CIN + G * 8;
        ldsA[ch] = c * 16;
        ldsB[ch] = ABYTES + c * 16;
    }

    // ds_read offsets: row r, k-granule g -> byte r*128 + ((g ^ (r&7))<<4)
    const int la = lane & 15, hq = lane >> 4, l7 = lane & 7;
    int aoff[2], boff[2];
#pragma unroll
    for (int kk = 0; kk < 2; kk++) {
        int g = (kk * 4 + hq) ^ l7;
        aoff[kk] = (wm * 64 + la) * 128 + (g << 4);
        boff[kk] = ABYTES + (wn * 32 + la) * 128 + (g << 4);
    }

    f32x4 yac[2][2][4][2];
#pragma unroll
    for (int x = 0; x < 2; x++)
#pragma unroll
        for (int y = 0; y < 2; y++)
#pragma unroll
            for (int mi = 0; mi < 4; mi++)
#pragma unroll
                for (int nj = 0; nj < 2; nj++) yac[x][y][mi][nj] = (f32x4){0.f, 0.f, 0.f, 0.f};
    f32x4 mac[4][2];
    const f32x4 fz = (f32x4){0.f, 0.f, 0.f, 0.f};

    bf16x8 aX[4], bX[2], aY[4], bY[2];   // kk0 double-buffer (named sets)
    bf16x8 a1[4], b1[2];                 // kk1 per-slot set

    auto stage = [&](int s) {
        char* sb = lds + (s & 3) * BUFSZ;
        const int pq = s >> 1, kb = (s & 1) * 64;
        gload16(pa[0] + pq * APQ + kb, sb + ldsA[0]);
        gload16(pa[1] + pq * APQ + kb, sb + ldsA[1]);
        gload16(pb[0] + (size_t)pq * BPQ + kb, sb + ldsB[0]);
        gload16(pb[1] + (size_t)pq * BPQ + kb, sb + ldsB[1]);
    };

    auto fold = [&](int pq) {            // M[pq] -> Y planes, uniform branches
        const int p = pq >> 2, q = pq & 3;
        const float s1p = (p >= 2) ? -1.f : 1.f;
        const float s1q = (q >= 2) ? -1.f : 1.f;
        if (p != 3 && q != 3) {
#pragma unroll
            for (int mi = 0; mi < 4; mi++)
#pragma unroll
                for (int nj = 0; nj < 2; nj++) yac[0][0][mi][nj] += mac[mi][nj];
        }
        if (p != 3 && q != 0) {
#pragma unroll
            for (int mi = 0; mi < 4; mi++)
#pragma unroll
                for (int nj = 0; nj < 2; nj++) yac[0][1][mi][nj] += s1q * mac[mi][nj];
        }
        if (p != 0 && q != 3) {
#pragma unroll
            for (int mi = 0; mi < 4; mi++)
#pragma unroll
                for (int nj = 0; nj < 2; nj++) yac[1][0][mi][nj] += s1p * mac[mi][nj];
        }
        if (p != 0 && q != 0) {
            const float s11 = s1p * s1q;
#pragma unroll
            for (int mi = 0; mi < 4; mi++)
#pragma unroll
                for (int nj = 0; nj < 2; nj++) yac[1][1][mi][nj] += s11 * mac[mi][nj];
        }
    };

#define SLOT(T, AIN, BIN, AOUT, BOUT, VMC, STG, PRE, INIT, LGK2)              \
    {                                                                          \
        const int t_ = (T);                                                    \
        if (STG) stage(t_ + 3);                                                \
        if ((VMC) == 8)      asm volatile("s_waitcnt vmcnt(8)");               \
        else if ((VMC) == 4) asm volatile("s_waitcnt vmcnt(4)");               \
        else if ((VMC) == 0) asm volatile("s_waitcnt vmcnt(0)");               \
        __builtin_amdgcn_s_barrier();                                          \
        __builtin_amdgcn_sched_barrier(0);                                     \
        {                                                                      \
            const char* rb_ = lds + (t_ & 3) * BUFSZ;                          \
            _Pragma("unroll")                                                  \
            for (int mi = 0; mi < 4; mi++)                                     \
                a1[mi] = *reinterpret_cast<const bf16x8*>(rb_ + aoff[1] + mi * 2048); \
            _Pragma("unroll")                                                  \
            for (int nj = 0; nj < 2; nj++)                                     \
                b1[nj] = *reinterpret_cast<const bf16x8*>(rb_ + boff[1] + nj * 2048); \
        }                                                                      \
        __builtin_amdgcn_sched_barrier(0);                                     \
        asm volatile("s_waitcnt lgkmcnt(6)");                                  \
        __builtin_amdgcn_sched_barrier(0);                                     \
        __builtin_amdgcn_s_setprio(1);                                         \
        _Pragma("unroll")                                                      \
        for (int mi = 0; mi < 4; mi++)                                         \
            _Pragma("unroll")                                                  \
            for (int nj = 0; nj < 2; nj++)                                     \
                mac[mi][nj] = __builtin_amdgcn_mfma_f32_16x16x32_bf16(         \
                    AIN[mi], BIN[nj], (INIT) ? fz : mac[mi][nj], 0, 0, 0);     \
        __builtin_amdgcn_s_setprio(0);                                         \
        if (PRE) {                                                             \
            const char* rb2_ = lds + ((t_ + 1) & 3) * BUFSZ;                   \
            _Pragma("unroll")                                                  \
            for (int mi = 0; mi < 4; mi++)                                     \
                AOUT[mi] = *reinterpret_cast<const bf16x8*>(rb2_ + aoff[0] + mi * 2048); \
            _Pragma("unroll")                                                  \
            for (int nj = 0; nj < 2; nj++)                                     \
                BOUT[nj] = *reinterpret_cast<const bf16x8*>(rb2_ + boff[0] + nj * 2048); \
        }                                                                      \
        __builtin_amdgcn_sched_barrier(0);                                     \
        if ((LGK2) == 6) asm volatile("s_waitcnt lgkmcnt(6)");                 \
        else             asm volatile("s_waitcnt lgkmcnt(0)");                 \
        __builtin_amdgcn_sched_barrier(0);                                     \
        __builtin_amdgcn_s_setprio(1);                                         \
        _Pragma("unroll")                                                      \
        for (int mi = 0; mi < 4; mi++)                                         \
            _Pragma("unroll")                                                  \
            for (int nj = 0; nj < 2; nj++)                                     \
                mac[mi][nj] = __builtin_amdgcn_mfma_f32_16x16x32_bf16(         \
                    a1[mi], b1[nj], mac[mi][nj], 0, 0, 0);                     \
        __builtin_amdgcn_s_setprio(0);                                         \
        __builtin_amdgcn_sched_barrier(0);                                     \
        __builtin_amdgcn_s_barrier();                                          \
    }

    // prologue: 3 stages in flight; kk0 regs for slot 0 -> set X
    stage(0); stage(1); stage(2);
    asm volatile("s_waitcnt vmcnt(8)");  // stage 0 complete
    __builtin_amdgcn_s_barrier();
    {
        const char* rb_ = lds;
#pragma unroll
        for (int mi = 0; mi < 4; mi++)
            aX[mi] = *reinterpret_cast<const bf16x8*>(rb_ + aoff[0] + mi * 2048);
#pragma unroll
        for (int nj = 0; nj < 2; nj++)
            bX[nj] = *reinterpret_cast<const bf16x8*>(rb_ + boff[0] + nj * 2048);
    }

    for (int tt = 0; tt < 28; tt += 2) {
        if (tt >= 2) fold((tt >> 1) - 1);
        SLOT(tt,     aX, bX, aY, bY, 8, true, true, true,  6)
        SLOT(tt + 1, aY, bY, aX, bX, 8, true, true, false, 6)
    }
    fold(13);
    SLOT(28, aX, bX, aY, bY, 8,  true,  true,  true,  6)
    SLOT(29, aY, bY, aX, bX, 4,  false, true,  false, 6)
    fold(14);
    SLOT(30, aX, bX, aY, bY, 0,  false, true,  true,  6)
    SLOT(31, aY, bY, aX, bX, -1, false, false, false, 0)
    fold(15);

#undef SLOT

    // ---- writeout: D frag: col(bij)=lane&15, row(kout)=(lane>>4)*4+r ----
    const int lr = lane & 15, rg = lane >> 4;
#pragma unroll
    for (int mi = 0; mi < 4; mi++) {
#pragma unroll
        for (int r = 0; r < 4; r++) {
            const int kout = m0 + wm * 64 + mi * 16 + rg * 4 + r;
            const float bvv = bias[kout];
#pragma unroll
            for (int nj = 0; nj < 2; nj++) {
                const int bij = n0 + wn * 32 + nj * 16 + lr;
                const int bb = bij >> 10, ti = (bij >> 5) & 31, tj = bij & 31;
                float* op = out + (((size_t)bb * COUT + kout) * HH + 2 * ti) * WW + 2 * tj;
                *reinterpret_cast<float2*>(op) =
                    make_float2(yac[0][0][mi][nj][r] + bvv, yac[0][1][mi][nj][r] + bvv);
                *reinterpret_cast<float2*>(op + WW) =
                    make_float2(yac[1][0][mi][nj][r] + bvv, yac[1][1][mi][nj][r] + bvv);
            }
        }
    }
}

// ---------------------------------------------------------------------------
extern "C" void kernel_launch(void* const* d_in, const int* in_sizes, int n_in,
                              void* d_out, int out_size, void* d_ws, size_t ws_size,
                              hipStream_t stream) {
    const float* X    = (const float*)d_in[0];
    const float* w    = (const float*)d_in[1];
    const float* bias = (const float*)d_in[2];
    float* out        = (float*)d_out;

    __hip_bfloat16* U = (__hip_bfloat16*)d_ws;                       // 1 MB
    __hip_bfloat16* V = (__hip_bfloat16*)((char*)d_ws + (1u << 20)); // 64 MB

    wg_wtrans<<<(COUT * CIN + 255) / 256, 256, 0, stream>>>(w, U);
    wg_itrans2<<<dim3(TH, BATCH), 1024, 0, stream>>>(X, V);
    wg_gemm13<<<(COUT / 128) * (NT / 128), 512, 0, stream>>>(U, V, bias, out);
}